// Round 16
// baseline (25.946 us; speedup 1.0000x reference)
//
#include <hip/hip_runtime.h>
#include <hip/hip_bf16.h>

// Problem constants (match reference)
#define NN 1024
#define FF 256
#define DD 64
#define RR 11
#define EE 2048
#define ALPHA 0.2f
#define TPB 512
#define EPT (EE / TPB)          // 4 edges per thread in K1
#define FB 4                    // features per K1 block
#define K1_GRID (FF / FB + 1)   // 64 feature blocks + 1 sort block
#define TILE_E 32               // edges per K2 tile (same relation)
#define PERM_CAP 2432           // >= 2048 + 11*31, = 76*32
#define K2_GRID (PERM_CAP / TILE_E)  // 76

// ws layout (bytes):
//   0     : int ntiles
//   256   : int perm[PERM_CAP]   (9728 B)
//   16384 : float cbuf[EE*FF]    (2 MB, e-major: cbuf[e*FF+f])

// K1: block b (0..63) owns features f0..f0+3, f0 = ((b&7)*8 + (b>>3))*4
//     [XCD k = b&7 owns features 32k..32k+31 = its own x 128B lines].
//     x staged via float4 ROW loads (16B granules, 4x fewer instructions
//     than per-feature column gathers). Single-pass softmax (|v|<~2).
//     Block 64: relation counting-sort into 32-padded buckets.
__global__ __launch_bounds__(TPB) void k1_coef(
    const float* __restrict__ x, const float* __restrict__ W,
    const float* __restrict__ a, const int* __restrict__ src,
    const int* __restrict__ dst, const int* __restrict__ rel,
    float* __restrict__ cbuf, int* __restrict__ perm,
    int* __restrict__ ntiles_p) {

    const int b    = blockIdx.x;   // 0..64
    const int tid  = threadIdx.x;  // 0..511
    const int wid  = tid >> 6;     // 0..7
    const int lane = tid & 63;

    __shared__ int hist[16], off_sh[16];

    if (b == FF / FB) {
        // dedicated sort block: counting sort by relation, 32-padded buckets
        if (tid < 16) hist[tid] = 0;
        __syncthreads();
        for (int e = tid; e < EE; e += TPB) atomicAdd(&hist[rel[e]], 1);
        __syncthreads();
        if (tid == 0) {
            int acc = 0;
            for (int r = 0; r < RR; ++r) {
                off_sh[r] = acc;
                acc += (hist[r] + TILE_E - 1) & ~(TILE_E - 1);
            }
            *ntiles_p = acc / TILE_E;
        }
        __syncthreads();
        for (int i = tid; i < PERM_CAP; i += TPB) perm[i] = -1;
        __syncthreads();
        for (int e = tid; e < EE; e += TPB) {
            int pos = atomicAdd(&off_sh[rel[e]], 1);
            perm[pos] = e;
        }
        return;
    }

    const int f0 = (((b & 7) << 3) | (b >> 3)) * FB;   // XCD-grouped 4-feature base

    __shared__ float xs[FB][NN];            // 16 KB: x[:, f0..f0+3]
    __shared__ float p_sh[FB][RR], q_sh[FB][RR];
    __shared__ float red_s[8];

    // stage 4 x-columns via float4 row loads (2 per thread, line-adjacent)
    #pragma unroll
    for (int i = 0; i < NN / TPB; ++i) {
        int row = tid + i * TPB;
        float4 v = *(const float4*)&x[(size_t)row * FF + f0];
        xs[0][row] = v.x; xs[1][row] = v.y; xs[2][row] = v.z; xs[3][row] = v.w;
    }

    // p/q for 4 features x 11 relations: 44 wave-dot tasks over 8 waves
    for (int task = wid; task < FB * RR; task += 8) {
        int ff = task & (FB - 1), r = task >> 2;
        float wv = W[((size_t)r * FF + f0 + ff) * DD + lane];
        float pa = wv * a[lane];
        float qa = wv * a[DD + lane];
        #pragma unroll
        for (int o = 32; o > 0; o >>= 1) {
            pa += __shfl_down(pa, o);
            qa += __shfl_down(qa, o);
        }
        if (lane == 0) { p_sh[ff][r] = pa; q_sh[ff][r] = qa; }
    }
    __syncthreads();   // xs + p_sh/q_sh ready

    // hoist edge indices once (shared across the 4 features)
    int siA[EPT], diA[EPT], rA[EPT];
    #pragma unroll
    for (int k = 0; k < EPT; ++k) {
        int e = tid + k * TPB;
        siA[k] = src[e]; diA[k] = dst[e]; rA[k] = rel[e];
    }

    // per owned feature: single-pass softmax + fused coefficient
    for (int ff = 0; ff < FB; ++ff) {
        float uvals[EPT];
        float s = 0.0f;
        #pragma unroll
        for (int k = 0; k < EPT; ++k) {
            float xsv = xs[ff][siA[k]];
            float xdd = xs[ff][diA[k]];
            float v = xsv * p_sh[ff][rA[k]] + xdd * q_sh[ff][rA[k]];
            v = v > 0.0f ? v : ALPHA * v;
            float ev = expf(v);
            uvals[k] = ev * xdd;
            s += ev;
        }
        #pragma unroll
        for (int o = 32; o > 0; o >>= 1) s += __shfl_down(s, o);
        if (lane == 0) red_s[wid] = s;
        __syncthreads();
        float st = red_s[0];
        #pragma unroll
        for (int i = 1; i < 8; ++i) st += red_s[i];
        __syncthreads();           // red_s reusable next ff
        float inv = 1.0f / st;

        #pragma unroll
        for (int k = 0; k < EPT; ++k) {
            int e = tid + k * TPB;
            cbuf[(size_t)e * FF + f0 + ff] = uvals[k] * inv;
        }
    }
}

// K2 (R15-proven): block = tile of 32 same-relation edges; 8 waves, wave = 4
//     edges. W_r streamed through LDS in double-buffered 8 KB chunks.
__global__ __launch_bounds__(TPB) void k2_out(
    const float* __restrict__ W, const int* __restrict__ rel,
    const float* __restrict__ cbuf, const int* __restrict__ perm,
    const int* __restrict__ ntiles_p, float* __restrict__ out) {

    const int t = blockIdx.x;      // 0..75
    if (t >= *ntiles_p) return;    // block-uniform

    const int tid  = threadIdx.x;
    const int wid  = tid >> 6;
    const int lane = tid & 63;

    __shared__ float Wl[32 * DD];  // 8 KB chunk: W_r[fc*32 .. +32][:]
    __shared__ int   e_sh[TILE_E];

    if (tid < TILE_E) e_sh[tid] = perm[t * TILE_E + tid];
    __syncthreads();

    const int r = rel[e_sh[0]];    // slot 0 of a tile is always a real edge
    const float* __restrict__ Wr = W + (size_t)r * FF * DD;

    int eb[4];
    const float* ce[4];
    float4 acc[4];
    #pragma unroll
    for (int j = 0; j < 4; ++j) {
        eb[j]  = e_sh[wid * 4 + j];
        ce[j]  = cbuf + (size_t)(eb[j] >= 0 ? eb[j] : 0) * FF;
        acc[j] = make_float4(0.f, 0.f, 0.f, 0.f);
    }

    const int fg = lane >> 4;      // 0..3: f within a 4-group
    const int dq = lane & 15;      // 0..15: d-quad
    const int srow = tid >> 4;     // 0..31: staging row
    const int scol = tid & 15;     // 0..15: staging float4 col

    // prefetch chunk 0
    float4 nxt = *(const float4*)&Wr[(size_t)srow * DD + scol * 4];

    #pragma unroll
    for (int fc = 0; fc < FF / 32; ++fc) {   // 8 chunks of 32 features
        __syncthreads();
        *(float4*)&Wl[srow * DD + scol * 4] = nxt;
        __syncthreads();
        if (fc < FF / 32 - 1)
            nxt = *(const float4*)
                &Wr[(size_t)((fc + 1) * 32 + srow) * DD + scol * 4];
        #pragma unroll
        for (int i = 0; i < 8; ++i) {
            int lf = i * 4 + fg;                        // local f 0..31
            float4 w4 = *(const float4*)&Wl[lf * DD + dq * 4];
            int gf = fc * 32 + lf;
            #pragma unroll
            for (int j = 0; j < 4; ++j) {
                float c = ce[j][gf];                    // broadcast/16 lanes
                acc[j].x = fmaf(c, w4.x, acc[j].x);
                acc[j].y = fmaf(c, w4.y, acc[j].y);
                acc[j].z = fmaf(c, w4.z, acc[j].z);
                acc[j].w = fmaf(c, w4.w, acc[j].w);
            }
        }
    }

    #pragma unroll
    for (int j = 0; j < 4; ++j) {
        #pragma unroll
        for (int o = 16; o <= 32; o <<= 1) {
            acc[j].x += __shfl_xor(acc[j].x, o);
            acc[j].y += __shfl_xor(acc[j].y, o);
            acc[j].z += __shfl_xor(acc[j].z, o);
            acc[j].w += __shfl_xor(acc[j].w, o);
        }
        if (eb[j] >= 0 && fg == 0)
            *(float4*)&out[(size_t)eb[j] * DD + dq * 4] = acc[j];
    }
}

extern "C" void kernel_launch(void* const* d_in, const int* in_sizes, int n_in,
                              void* d_out, int out_size, void* d_ws, size_t ws_size,
                              hipStream_t stream) {
    const float* x  = (const float*)d_in[0];   // [N, F]
    const float* W  = (const float*)d_in[1];   // [R, F, D]
    const float* a  = (const float*)d_in[2];   // [2*D]
    const int* src  = (const int*)d_in[3];     // [E]
    const int* dst  = (const int*)d_in[4];     // [E]
    const int* rel  = (const int*)d_in[5];     // [E]
    float* out      = (float*)d_out;           // [E*D]

    char* wsb = (char*)d_ws;
    int*   ntiles_p = (int*)wsb;
    int*   perm     = (int*)(wsb + 256);
    float* cbuf     = (float*)(wsb + 16384);

    k1_coef<<<K1_GRID, TPB, 0, stream>>>(x, W, a, src, dst, rel,
                                         cbuf, perm, ntiles_p);
    k2_out<<<K2_GRID, TPB, 0, stream>>>(W, rel, cbuf, perm, ntiles_p, out);
}

// Round 17
// 19.950 us; speedup vs baseline: 1.3006x; 1.3006x over previous
//
#include <hip/hip_runtime.h>
#include <hip/hip_bf16.h>

// Problem constants (match reference)
#define NN 1024
#define FF 256
#define DD 64
#define RR 11
#define EE 2048
#define ALPHA 0.2f
#define TPB 512
#define EPT (EE / TPB)          // 4 edges per thread in K1
#define TILE_E 32               // edges per K2 tile (same relation)
#define PERM_CAP 2432           // >= 2048 + 11*31, = 76*32
#define K2_GRID (PERM_CAP / TILE_E)  // 76

// ws layout (bytes):
//   0     : int perm[PERM_CAP]   (9728 B)
//   16384 : float cbuf[EE*FF]    (2 MB, e-major: cbuf[e*FF+f])
// No ntiles: K2 tiles guard on e_sh[0] < 0 (32-aligned buckets fill from
// the base, so any real tile has slot 0 occupied).

// K1: blocks 0..255 own feature f=(b&7)*32+(b>>3) [XCD-grouped]. Stage
//     x[:,f] in LDS; p/q wave-dots; single-pass softmax (|v|<~2, R12-proven);
//     write c[e,f]=exp(v)*xd/sum (e-major). Block 256: dedicated relation
//     counting-sort (runs CONCURRENTLY with feature blocks -> no straggler).
__global__ __launch_bounds__(TPB) void k1_coef(
    const float* __restrict__ x, const float* __restrict__ W,
    const float* __restrict__ a, const int* __restrict__ src,
    const int* __restrict__ dst, const int* __restrict__ rel,
    float* __restrict__ cbuf, int* __restrict__ perm) {

    const int b    = blockIdx.x;   // 0..256
    const int tid  = threadIdx.x;  // 0..511
    const int wid  = tid >> 6;     // 0..7
    const int lane = tid & 63;

    __shared__ int hist[16], off_sh[16];

    if (b == FF) {
        // dedicated sort block: counting sort by relation, 32-padded buckets
        if (tid < 16) hist[tid] = 0;
        __syncthreads();
        for (int e = tid; e < EE; e += TPB) atomicAdd(&hist[rel[e]], 1);
        __syncthreads();
        if (tid == 0) {
            int acc = 0;
            for (int r = 0; r < RR; ++r) {
                off_sh[r] = acc;
                acc += (hist[r] + TILE_E - 1) & ~(TILE_E - 1);
            }
        }
        __syncthreads();
        for (int i = tid; i < PERM_CAP; i += TPB) perm[i] = -1;
        __syncthreads();
        for (int e = tid; e < EE; e += TPB) {
            int pos = atomicAdd(&off_sh[rel[e]], 1);
            perm[pos] = e;
        }
        return;
    }

    const int f = ((b & 7) << 5) | (b >> 3);   // XCD-grouped feature

    __shared__ float xcol[NN];     // 4 KB: x[:, f]
    __shared__ float p_sh[RR], q_sh[RR];
    __shared__ float red_s[8];

    // stage column f of x (lines L2-shared within this XCD)
    for (int i = tid; i < NN; i += TPB) xcol[i] = x[(size_t)i * FF + f];

    // own-feature p/q: p[r]=dot(W[r,f,:],a[:64]), q[r]=dot(W[r,f,:],a[64:])
    for (int r = wid; r < RR; r += 8) {
        float w  = W[((size_t)r * FF + f) * DD + lane];
        float pa = w * a[lane];
        float qa = w * a[DD + lane];
        #pragma unroll
        for (int o = 32; o > 0; o >>= 1) {
            pa += __shfl_down(pa, o);
            qa += __shfl_down(qa, o);
        }
        if (lane == 0) { p_sh[r] = pa; q_sh[r] = qa; }
    }
    __syncthreads();   // xcol + p_sh/q_sh ready

    // single pass: u = exp(v)*xd, s = sum(exp(v))
    float uvals[EPT];
    float s = 0.0f;
    #pragma unroll
    for (int k = 0; k < EPT; ++k) {
        int e = tid + k * TPB;
        float xs = xcol[src[e]];
        float xd = xcol[dst[e]];
        int r = rel[e];
        float v = xs * p_sh[r] + xd * q_sh[r];
        v = v > 0.0f ? v : ALPHA * v;
        float ev = expf(v);
        uvals[k] = ev * xd;
        s += ev;
    }
    #pragma unroll
    for (int o = 32; o > 0; o >>= 1) s += __shfl_down(s, o);
    if (lane == 0) red_s[wid] = s;
    __syncthreads();
    float st = red_s[0];
    #pragma unroll
    for (int i = 1; i < 8; ++i) st += red_s[i];
    float inv = 1.0f / st;

    // fused coefficient c[e,f] = attn[e,f]*x[dst,f], e-major
    #pragma unroll
    for (int k = 0; k < EPT; ++k) {
        int e = tid + k * TPB;
        cbuf[(size_t)e * FF + f] = uvals[k] * inv;
    }
}

// K2: block = tile of 32 same-relation edges; 8 waves, wave = 4 edges.
//     W_r streamed through PING-PONG LDS buffers (one barrier per chunk).
//     Guard: e_sh[0] < 0 -> empty tile (no ntiles dependency).
__global__ __launch_bounds__(TPB) void k2_out(
    const float* __restrict__ W, const int* __restrict__ rel,
    const float* __restrict__ cbuf, const int* __restrict__ perm,
    float* __restrict__ out) {

    const int t    = blockIdx.x;   // 0..75
    const int tid  = threadIdx.x;
    const int wid  = tid >> 6;
    const int lane = tid & 63;

    __shared__ float Wl[2][32 * DD];   // 2 x 8 KB ping-pong chunks
    __shared__ int   e_sh[TILE_E];

    if (tid < TILE_E) e_sh[tid] = perm[t * TILE_E + tid];
    __syncthreads();

    if (e_sh[0] < 0) return;       // fully-padded tile (beyond last bucket)

    const int r = rel[e_sh[0]];
    const float* __restrict__ Wr = W + (size_t)r * FF * DD;

    int eb[4];
    const float* ce[4];
    float4 acc[4];
    #pragma unroll
    for (int j = 0; j < 4; ++j) {
        eb[j]  = e_sh[wid * 4 + j];
        ce[j]  = cbuf + (size_t)(eb[j] >= 0 ? eb[j] : 0) * FF;
        acc[j] = make_float4(0.f, 0.f, 0.f, 0.f);
    }

    const int fg = lane >> 4;      // 0..3: f within a 4-group
    const int dq = lane & 15;      // 0..15: d-quad
    const int srow = tid >> 4;     // 0..31: staging row
    const int scol = tid & 15;     // 0..15: staging float4 col

    // stage chunk 0
    *(float4*)&Wl[0][srow * DD + scol * 4] =
        *(const float4*)&Wr[(size_t)srow * DD + scol * 4];
    __syncthreads();

    #pragma unroll
    for (int fc = 0; fc < FF / 32; ++fc) {   // 8 chunks of 32 features
        float4 nxt;
        if (fc < FF / 32 - 1)                // issue next load; hides under FMAs
            nxt = *(const float4*)
                &Wr[(size_t)((fc + 1) * 32 + srow) * DD + scol * 4];

        const float* Wc = Wl[fc & 1];
        #pragma unroll
        for (int i = 0; i < 8; ++i) {
            int lf = i * 4 + fg;                        // local f 0..31
            float4 w4 = *(const float4*)&Wc[lf * DD + dq * 4];
            int gf = fc * 32 + lf;
            #pragma unroll
            for (int j = 0; j < 4; ++j) {
                float c = ce[j][gf];                    // broadcast/16 lanes
                acc[j].x = fmaf(c, w4.x, acc[j].x);
                acc[j].y = fmaf(c, w4.y, acc[j].y);
                acc[j].z = fmaf(c, w4.z, acc[j].z);
                acc[j].w = fmaf(c, w4.w, acc[j].w);
            }
        }

        if (fc < FF / 32 - 1) {              // write other buffer, one barrier
            *(float4*)&Wl[(fc + 1) & 1][srow * DD + scol * 4] = nxt;
            __syncthreads();
        }
    }

    // per edge: sum the 4 f-groups (lanes l, l^16, l^32, l^48 share d-quad)
    #pragma unroll
    for (int j = 0; j < 4; ++j) {
        #pragma unroll
        for (int o = 16; o <= 32; o <<= 1) {
            acc[j].x += __shfl_xor(acc[j].x, o);
            acc[j].y += __shfl_xor(acc[j].y, o);
            acc[j].z += __shfl_xor(acc[j].z, o);
            acc[j].w += __shfl_xor(acc[j].w, o);
        }
        if (eb[j] >= 0 && fg == 0)
            *(float4*)&out[(size_t)eb[j] * DD + dq * 4] = acc[j];
    }
}

extern "C" void kernel_launch(void* const* d_in, const int* in_sizes, int n_in,
                              void* d_out, int out_size, void* d_ws, size_t ws_size,
                              hipStream_t stream) {
    const float* x  = (const float*)d_in[0];   // [N, F]
    const float* W  = (const float*)d_in[1];   // [R, F, D]
    const float* a  = (const float*)d_in[2];   // [2*D]
    const int* src  = (const int*)d_in[3];     // [E]
    const int* dst  = (const int*)d_in[4];     // [E]
    const int* rel  = (const int*)d_in[5];     // [E]
    float* out      = (float*)d_out;           // [E*D]

    char* wsb = (char*)d_ws;
    int*   perm = (int*)wsb;
    float* cbuf = (float*)(wsb + 16384);

    k1_coef<<<FF + 1, TPB, 0, stream>>>(x, W, a, src, dst, rel, cbuf, perm);
    k2_out<<<K2_GRID, TPB, 0, stream>>>(W, rel, cbuf, perm, out);
}